// Round 7
// baseline (287.351 us; speedup 1.0000x reference)
//
#include <hip/hip_runtime.h>
#include <hip/hip_bf16.h>
#include <math.h>

// Problem constants
#define TT 243
#define CC 544            // J*IC
#define NBB 81            // T/BS
#define KK 6
#define HH 8
#define HD 68             // C/H
#define DEPTH 2
#define HID 1088          // 2*C
#define BB 512
#define MTOK 3072         // B*K tokens
#define EPSF 1e-6f

typedef __attribute__((ext_vector_type(8))) short bf16x8;
typedef __attribute__((ext_vector_type(4))) float f32x4;

__device__ __forceinline__ __hip_bfloat16 f2b(float f) { return __float2bfloat16(f); }
__device__ __forceinline__ unsigned short f2bu(float f) {
    __hip_bfloat16 h = __float2bfloat16(f);
    return *(unsigned short*)&h;
}
__device__ __forceinline__ float b2f_lo(unsigned int u) { return __uint_as_float(u << 16); }
__device__ __forceinline__ float b2f_hi(unsigned int u) { return __uint_as_float(u & 0xffff0000u); }

// weight conversion segment ends (float4-index space): qkv | proj | mfc1 | mfc2
#define E0 443904      // 2*1632*544/4
#define E1 591872      // +2*544*544/4
#define E2 887808      // +2*1088*544/4
#define E3 1183744     // +2*544*1088/4

// bw_kernel block ranges
#define RS_BLOCKS 3888            // 3888*32 rows = 124416 = 512*243
#define PS_BLOCKS 8               // 8*32 = 256 >= 243 pos rows
#define WC_BLOCKS 4624            // E3/256
#define BW_GRID (RS_BLOCKS + PS_BLOCKS + WC_BLOCKS)

// ---------------------------------------------------------------------------
// bw_kernel: pure-bandwidth work in one dispatch.
// ---------------------------------------------------------------------------
__global__ __launch_bounds__(256, 4) void bw_kernel(
    const float* __restrict__ x,     // B*T*C
    const float* __restrict__ pos,   // T*C
    const float* __restrict__ qkvw, const float* __restrict__ projw,
    const float* __restrict__ mfc1w, const float* __restrict__ mfc2w,
    unsigned short* __restrict__ wbf,
    float* __restrict__ L,           // B*T  (x-only)
    float* __restrict__ R,           // B*T  (x-only)
    float* __restrict__ pLR)         // 2*T: pL | pR
{
    const int blk = blockIdx.x;
    const int tid = threadIdx.x;

    if (blk < RS_BLOCKS) {
        const int w = tid >> 6;
        const int lane = tid & 63;
        const int oct = lane & 7;
        const int rsub = lane >> 3;
        const int r = (blk * 4 + w) * 8 + rsub;          // 0..124415
        const float4* xr = (const float4*)x + (size_t)r * 136;
        float4 xs[17];
#pragma unroll
        for (int j = 0; j < 17; ++j) xs[j] = xr[oct + j * 8];
        float aL = 0.0f, aR = 0.0f;
#pragma unroll
        for (int j = 0; j < 17; ++j) {
            const float s = (xs[j].x + xs[j].y) + (xs[j].z + xs[j].w);
            if (j < 8) aL += s;
            else if (j == 8) { if (oct < 4) aL += s; else aR += s; }
            else aR += s;
        }
#pragma unroll
        for (int m = 1; m < 8; m <<= 1) {
            aL += __shfl_xor(aL, m);
            aR += __shfl_xor(aR, m);
        }
        if (oct == 0) { L[r] = aL; R[r] = aR; }
        return;
    }

    if (blk < RS_BLOCKS + PS_BLOCKS) {
        const int w = tid >> 6;
        const int lane = tid & 63;
        const int oct = lane & 7;
        const int rsub = lane >> 3;
        const int r = (blk - RS_BLOCKS) * 32 + w * 8 + rsub;   // 0..255
        const int rc = (r < TT) ? r : (TT - 1);
        const float4* pr = (const float4*)pos + (size_t)rc * 136;
        float4 xs[17];
#pragma unroll
        for (int j = 0; j < 17; ++j) xs[j] = pr[oct + j * 8];
        float aL = 0.0f, aR = 0.0f;
#pragma unroll
        for (int j = 0; j < 17; ++j) {
            const float s = (xs[j].x + xs[j].y) + (xs[j].z + xs[j].w);
            if (j < 8) aL += s;
            else if (j == 8) { if (oct < 4) aL += s; else aR += s; }
            else aR += s;
        }
#pragma unroll
        for (int m = 1; m < 8; m <<= 1) {
            aL += __shfl_xor(aL, m);
            aR += __shfl_xor(aR, m);
        }
        if (oct == 0 && r < TT) { pLR[r] = aL; pLR[TT + r] = aR; }
        return;
    }

    // ---- weight conversion ----
    const int i = (blk - RS_BLOCKS - PS_BLOCKS) * 256 + tid;
    if (i < E3) {
        float4 v;
        if (i < E0)      v = ((const float4*)qkvw)[i];
        else if (i < E1) v = ((const float4*)projw)[i - E0];
        else if (i < E2) v = ((const float4*)mfc1w)[i - E1];
        else             v = ((const float4*)mfc2w)[i - E2];
        ushort4 o;
        o.x = f2bu(v.x); o.y = f2bu(v.y); o.z = f2bu(v.z); o.w = f2bu(v.w);
        ((ushort4*)wbf)[i] = o;
    }
}

// ---------------------------------------------------------------------------
// select: per-b: y0 from L/R(+pos sums), LDS-staged 81x81 MLP x2, sigmoid,
//         top-6, gather t from x+pos (f32 only; LN moved into qkv GEMM)
// ---------------------------------------------------------------------------
__global__ __launch_bounds__(128) void select_kernel(
    const float* __restrict__ L,     // B*T (x-only)
    const float* __restrict__ R,     // B*T
    const float* __restrict__ pLR,   // 2*T
    const float* __restrict__ fc1,   // 81*81
    const float* __restrict__ fc2,   // 81*81
    const float* __restrict__ x,     // B*T*C
    const float* __restrict__ pos,   // T*C
    float* __restrict__ t)           // B*6*544 f32
{
    const int b = blockIdx.x;
    const int tid = threadIdx.x;
    __shared__ float sf1[NBB * NBB];
    __shared__ float sf2[NBB * NBB];
    __shared__ float sy[NBB], sz[NBB], swv[NBB];
    __shared__ int sidx[KK];

    const int w = tid >> 6;
    const int lane = tid & 63;
    const float4* x4 = (const float4*)x;
    const float4* p4 = (const float4*)pos;

    // stage fc1/fc2 into LDS (coalesced)
    for (int i = tid; i < NBB * NBB; i += 128) {
        sf1[i] = fc1[i];
        sf2[i] = fc2[i];
    }

    // y0
    if (tid < NBB) {
        const int n = tid;
        const float* Lb = L + (size_t)b * TT;
        const float* Rb = R + (size_t)b * TT;
        const float* pL = pLR;
        const float* pR = pLR + TT;
        float s = Lb[3 * n] + Lb[3 * n + 1] + Rb[3 * n] + Rb[3 * n + 1] + Rb[3 * n + 2]
                + pL[3 * n] + pL[3 * n + 1] + pR[3 * n] + pR[3 * n + 1] + pR[3 * n + 2];
        if (n > 0) s += Lb[3 * n - 1] + pL[3 * n - 1];
        sy[n] = s * (1.0f / (3.0f * (float)CC));
    }
    __syncthreads();
    if (tid < NBB) {
        float s = 0.0f;
        for (int j = 0; j < NBB; ++j) s += sf1[tid * NBB + j] * sy[j];
        sz[tid] = fmaxf(s, 0.0f);
    }
    __syncthreads();
    if (tid < NBB) {
        float s = 0.0f;
        for (int j = 0; j < NBB; ++j) s += sf2[tid * NBB + j] * sz[j];
        swv[tid] = 1.0f / (1.0f + expf(-s));
    }
    __syncthreads();
    // wave-parallel top-6 (wave 0); tie-break: lowest index (matches top_k)
    if (w == 0) {
        float va = (lane < NBB) ? swv[lane] : -1e30f;
        float vb = (lane + 64 < NBB) ? swv[lane + 64] : -1e30f;
        const int ia = lane, ib = lane + 64;
        for (int kk = 0; kk < KK; ++kk) {
            float v = va; int idx = ia;
            if (vb > v) { v = vb; idx = ib; }
#pragma unroll
            for (int m = 1; m < 64; m <<= 1) {
                const float ov = __shfl_xor(v, m);
                const int oi = __shfl_xor(idx, m);
                if (ov > v || (ov == v && oi < idx)) { v = ov; idx = oi; }
            }
            if (lane == 0) sidx[kk] = idx;
            if (ia == idx) va = -1e30f;
            if (ib == idx) vb = -1e30f;
        }
    }
    __syncthreads();

    // gather -> t (global f32)
    for (int i = tid; i < KK * 136; i += 128) {
        const int k = i / 136;
        const int c4 = i - k * 136;
        const int n = sidx[k];
        const int shift = (c4 < 68) ? -1 : 0;
        float ax = 0.f, ay = 0.f, az = 0.f, aw = 0.f;
#pragma unroll
        for (int i2 = 0; i2 < 3; ++i2) {
            const int ttr = 3 * n + i2 + shift;
            if (ttr >= 0) {
                const float4 xv = x4[((size_t)b * TT + ttr) * 136 + c4];
                const float4 pv = p4[(size_t)ttr * 136 + c4];
                ax += xv.x + pv.x; ay += xv.y + pv.y; az += xv.z + pv.z; aw += xv.w + pv.w;
            }
        }
        const float inv3 = 1.0f / 3.0f;
        ((float4*)t)[((size_t)b * KK + k) * 136 + c4] =
            make_float4(ax * inv3, ay * inv3, az * inv3, aw * inv3);
    }
}

// ---------------------------------------------------------------------------
// bf16 MFMA GEMM with optional fused LayerNorm on A (LNA=1: X is f32, LN'd
// on the fly with stats computed in a prologue).
// Y[M,N] = act(A @ W^T + bias) (+R). 128x128 tile, BK=32, 4 waves 2x2.
// ---------------------------------------------------------------------------
template <int LNA, int ACT, int RES, int OBF>
__global__ __launch_bounds__(256) void gemm_mfma_kernel(
    const void* __restrict__ Xv,            // LNA ? f32 M x K : bf16 M x K
    const unsigned short* __restrict__ W,   // bf16 N x K
    const float* __restrict__ bias,         // N
    const float* __restrict__ Rr,           // M x N f32 residual or null
    const float* __restrict__ lng,          // K (LNA only)
    const float* __restrict__ lnb,          // K (LNA only)
    void* __restrict__ Y,                   // f32 or bf16
    int M, int N, int Kd)
{
    const int bm = blockIdx.y * 128;
    const int bn = blockIdx.x * 128;
    const int tid = threadIdx.x;
    const int K8 = Kd >> 3;    // bf16 uint4 per row
    const int K4 = Kd >> 2;    // f32 float4 per row

    __shared__ __align__(16) short As[128][40];
    __shared__ __align__(16) short Bs[128][40];
    __shared__ float smean[LNA ? 128 : 1];
    __shared__ float sinv[LNA ? 128 : 1];
    __shared__ float sg[LNA ? CC : 1];
    __shared__ float sb[LNA ? CC : 1];

    const int r0 = tid >> 2;           // rows 0..63
    const int c0 = tid & 3;            // chunk 0..3
    const int r1 = r0 + 64;            // rows 64..127
    const int wid = tid >> 6;
    const int lane = tid & 63;
    const int wm = (wid >> 1) * 64;
    const int wn = (wid & 1) * 64;
    const int l16 = lane & 15;
    const int l4 = lane >> 4;
    const int koff = l4 * 8;

    if constexpr (LNA) {
        // stage gamma/beta
        for (int i = tid; i < 136; i += 256) {
            ((float4*)sg)[i] = ((const float4*)lng)[i];
            ((float4*)sb)[i] = ((const float4*)lnb)[i];
        }
        // row stats: 8 lanes/row, 17 reg-buffered loads (K = 544 only)
        const float4* Xf = (const float4*)Xv;
        const int oct = lane & 7;
        const int rsub = lane >> 3;
#pragma unroll
        for (int p = 0; p < 4; ++p) {
            const int row = p * 32 + wid * 8 + rsub;
            const float4* tr = Xf + (size_t)(bm + row) * 136;
            float4 xs[17];
#pragma unroll
            for (int j = 0; j < 17; ++j) xs[j] = tr[oct + j * 8];
            float s = 0.f, s2 = 0.f;
#pragma unroll
            for (int j = 0; j < 17; ++j) {
                s += (xs[j].x + xs[j].y) + (xs[j].z + xs[j].w);
                s2 += xs[j].x * xs[j].x + xs[j].y * xs[j].y
                    + xs[j].z * xs[j].z + xs[j].w * xs[j].w;
            }
#pragma unroll
            for (int m = 1; m < 8; m <<= 1) {
                s += __shfl_xor(s, m);
                s2 += __shfl_xor(s2, m);
            }
            if (oct == 0) {
                const float mm = s / (float)CC;
                smean[row] = mm;
                sinv[row] = rsqrtf(s2 / (float)CC - mm * mm + EPSF);
            }
        }
        __syncthreads();
    }

    f32x4 acc[4][4] = {};

    const uint4* Wu = (const uint4*)W;
    const int wr0 = min(bn + r0, N - 1);
    const int wr1 = min(bn + r1, N - 1);

    uint4 a0, a1;
    float4 f00, f01, f10, f11;
    if constexpr (LNA) {
        const float4* Xf = (const float4*)Xv;
        const size_t base0 = (size_t)(bm + r0) * K4 + c0 * 2;
        const size_t base1 = (size_t)(bm + r1) * K4 + c0 * 2;
        f00 = Xf[base0]; f01 = Xf[base0 + 1];
        f10 = Xf[base1]; f11 = Xf[base1 + 1];
    } else {
        const uint4* Xu = (const uint4*)Xv;
        a0 = Xu[(size_t)(bm + r0) * K8 + c0];
        a1 = Xu[(size_t)(bm + r1) * K8 + c0];
    }
    uint4 b0 = Wu[(size_t)wr0 * K8 + c0];
    uint4 b1 = Wu[(size_t)wr1 * K8 + c0];

    const int nk = Kd >> 5;
    for (int kt = 0; kt < nk; ++kt) {
        __syncthreads();
        if constexpr (LNA) {
            const int cb = kt * 32 + c0 * 8;
            const float m0 = smean[r0], i0 = sinv[r0];
            const float m1 = smean[r1], i1 = sinv[r1];
            ushort4 o;
            o.x = f2bu((f00.x - m0) * i0 * sg[cb + 0] + sb[cb + 0]);
            o.y = f2bu((f00.y - m0) * i0 * sg[cb + 1] + sb[cb + 1]);
            o.z = f2bu((f00.z - m0) * i0 * sg[cb + 2] + sb[cb + 2]);
            o.w = f2bu((f00.w - m0) * i0 * sg[cb + 3] + sb[cb + 3]);
            *(ushort4*)&As[r0][c0 * 8] = o;
            o.x = f2bu((f01.x - m0) * i0 * sg[cb + 4] + sb[cb + 4]);
            o.y = f2bu((f01.y - m0) * i0 * sg[cb + 5] + sb[cb + 5]);
            o.z = f2bu((f01.z - m0) * i0 * sg[cb + 6] + sb[cb + 6]);
            o.w = f2bu((f01.w - m0) * i0 * sg[cb + 7] + sb[cb + 7]);
            *(ushort4*)&As[r0][c0 * 8 + 4] = o;
            o.x = f2bu((f10.x - m1) * i1 * sg[cb + 0] + sb[cb + 0]);
            o.y = f2bu((f10.y - m1) * i1 * sg[cb + 1] + sb[cb + 1]);
            o.z = f2bu((f10.z - m1) * i1 * sg[cb + 2] + sb[cb + 2]);
            o.w = f2bu((f10.w - m1) * i1 * sg[cb + 3] + sb[cb + 3]);
            *(ushort4*)&As[r1][c0 * 8] = o;
            o.x = f2bu((f11.x - m1) * i1 * sg[cb + 4] + sb[cb + 4]);
            o.y = f2bu((f11.y - m1) * i1 * sg[cb + 5] + sb[cb + 5]);
            o.z = f2bu((f11.z - m1) * i1 * sg[cb + 6] + sb[cb + 6]);
            o.w = f2bu((f11.w - m1) * i1 * sg[cb + 7] + sb[cb + 7]);
            *(ushort4*)&As[r1][c0 * 8 + 4] = o;
        } else {
            *(uint4*)&As[r0][c0 * 8] = a0;
            *(uint4*)&As[r1][c0 * 8] = a1;
        }
        *(uint4*)&Bs[r0][c0 * 8] = b0;
        *(uint4*)&Bs[r1][c0 * 8] = b1;
        __syncthreads();

        const bool more = (kt + 1 < nk);
        if (more) {
            if constexpr (LNA) {
                const float4* Xf = (const float4*)Xv;
                const size_t base0 = (size_t)(bm + r0) * K4 + (kt + 1) * 8 + c0 * 2;
                const size_t base1 = (size_t)(bm + r1) * K4 + (kt + 1) * 8 + c0 * 2;
                f00 = Xf[base0]; f01 = Xf[base0 + 1];
                f10 = Xf[base1]; f11 = Xf[base1 + 1];
            } else {
                const uint4* Xu = (const uint4*)Xv;
                const int kc = (kt + 1) * 4 + c0;
                a0 = Xu[(size_t)(bm + r0) * K8 + kc];
                a1 = Xu[(size_t)(bm + r1) * K8 + kc];
            }
            const int kc = (kt + 1) * 4 + c0;
            b0 = Wu[(size_t)wr0 * K8 + kc];
            b1 = Wu[(size_t)wr1 * K8 + kc];
        }

        bf16x8 af[4], bf[4];
#pragma unroll
        for (int mf = 0; mf < 4; ++mf) af[mf] = *(const bf16x8*)&As[wm + mf * 16 + l16][koff];
#pragma unroll
        for (int nf = 0; nf < 4; ++nf) bf[nf] = *(const bf16x8*)&Bs[wn + nf * 16 + l16][koff];
#pragma unroll
        for (int mf = 0; mf < 4; ++mf)
#pragma unroll
            for (int nf = 0; nf < 4; ++nf)
                acc[mf][nf] = __builtin_amdgcn_mfma_f32_16x16x32_bf16(af[mf], bf[nf], acc[mf][nf], 0, 0, 0);
    }

    // epilogue
#pragma unroll
    for (int nf = 0; nf < 4; ++nf) {
        const int col = bn + wn + nf * 16 + l16;
        if (col < N) {
            const float bs = bias[col];
#pragma unroll
            for (int mf = 0; mf < 4; ++mf) {
#pragma unroll
                for (int j = 0; j < 4; ++j) {
                    const int row = bm + wm + mf * 16 + l4 * 4 + j;
                    float v = acc[mf][nf][j] + bs;
                    if (ACT == 1) v = 0.5f * v * (1.0f + erff(v * 0.70710678118654752f));
                    if (RES) v += Rr[(size_t)row * N + col];
                    if (OBF) ((__hip_bfloat16*)Y)[(size_t)row * N + col] = f2b(v);
                    else     ((float*)Y)[(size_t)row * N + col] = v;
                }
            }
        }
    }
}

// ---------------------------------------------------------------------------
// Attention: per block b; 8 waves = 8 heads; 6 tokens, head dim 68
// ---------------------------------------------------------------------------
__global__ __launch_bounds__(512) void attn_kernel(
    const unsigned short* __restrict__ qkv,  // B*6*1632 bf16
    __hip_bfloat16* __restrict__ o)          // B*6*544 bf16
{
    const int b = blockIdx.x;
    __shared__ __align__(16) float sq[KK * 3 * CC];
    __shared__ float sp[HH][40];
    const int tid = threadIdx.x;

    const uint4* src4 = (const uint4*)(qkv + (size_t)b * KK * 3 * CC);  // 1224 uint4
    for (int i = tid; i < (KK * 3 * CC) / 8; i += 512) {
        const uint4 u = src4[i];
        float4 f0, f1;
        f0.x = b2f_lo(u.x); f0.y = b2f_hi(u.x);
        f0.z = b2f_lo(u.y); f0.w = b2f_hi(u.y);
        f1.x = b2f_lo(u.z); f1.y = b2f_hi(u.z);
        f1.z = b2f_lo(u.w); f1.w = b2f_hi(u.w);
        ((float4*)sq)[2 * i] = f0;
        ((float4*)sq)[2 * i + 1] = f1;
    }
    __syncthreads();

    const int h = tid >> 6;
    const int lane = tid & 63;
    const float scl = rsqrtf((float)HD);

    if (lane < KK * KK) {
        const int n = lane / KK, m = lane - (lane / KK) * KK;
        const float* qp = &sq[n * (3 * CC) + 0 * CC + h * HD];
        const float* kp = &sq[m * (3 * CC) + 1 * CC + h * HD];
        float s = 0.0f;
#pragma unroll 4
        for (int d = 0; d < HD; ++d) s += qp[d] * kp[d];
        sp[h][lane] = s * scl;
    }
    __syncthreads();
    if (lane < KK) {
        const int n = lane;
        float mx = -1e30f;
#pragma unroll
        for (int m = 0; m < KK; ++m) mx = fmaxf(mx, sp[h][n * KK + m]);
        float e[KK];
        float sum = 0.0f;
#pragma unroll
        for (int m = 0; m < KK; ++m) { e[m] = expf(sp[h][n * KK + m] - mx); sum += e[m]; }
        const float inv = 1.0f / sum;
#pragma unroll
        for (int m = 0; m < KK; ++m) sp[h][n * KK + m] = e[m] * inv;
    }
    __syncthreads();
    for (int i = tid; i < KK * CC; i += 512) {
        const int n = i / CC;
        const int cd = i - n * CC;
        const int hh = cd / HD;
        const int d = cd - hh * HD;
        float acc = 0.0f;
#pragma unroll
        for (int m = 0; m < KK; ++m)
            acc += sp[hh][n * KK + m] * sq[m * (3 * CC) + 2 * CC + hh * HD + d];
        o[(size_t)b * KK * CC + i] = f2b(acc);
    }
}

// ---------------------------------------------------------------------------
// Final: LN(t) with lnf, then out[b,c] = sum_k tln[b,k,c]*wm2_w[k] + wm2_b
// ---------------------------------------------------------------------------
__global__ __launch_bounds__(256) void final_kernel(
    const float* __restrict__ t,     // B*6*544
    const float* __restrict__ g,
    const float* __restrict__ bta,
    const float* __restrict__ wm2w,  // 6
    const float* __restrict__ wm2b,  // 1
    float* __restrict__ out)         // B*544
{
    const int b = blockIdx.x;
    const int tid = threadIdx.x;
    __shared__ float st[KK][CC];
    __shared__ float sm[KK], si[KK];
    const float* tb = t + (size_t)b * KK * CC;
    for (int i = tid; i < KK * CC; i += 256) st[i / CC][i % CC] = tb[i];
    __syncthreads();
    const int wid = tid >> 6, lane = tid & 63;
    for (int r = wid; r < KK; r += 4) {
        float s = 0.0f, s2 = 0.0f;
        for (int c = lane; c < CC; c += 64) { const float v = st[r][c]; s += v; s2 += v * v; }
#pragma unroll
        for (int off = 32; off; off >>= 1) { s += __shfl_xor(s, off); s2 += __shfl_xor(s2, off); }
        if (lane == 0) {
            const float m = s / (float)CC;
            sm[r] = m;
            si[r] = rsqrtf(s2 / (float)CC - m * m + EPSF);
        }
    }
    __syncthreads();
    const float w0 = wm2w[0], w1 = wm2w[1], w2 = wm2w[2], w3 = wm2w[3], w4 = wm2w[4], w5 = wm2w[5];
    const float wb = wm2b[0];
    for (int c = tid; c < CC; c += 256) {
        const float gg = g[c], bb = bta[c];
        float acc = wb;
        acc += w0 * ((st[0][c] - sm[0]) * si[0] * gg + bb);
        acc += w1 * ((st[1][c] - sm[1]) * si[1] * gg + bb);
        acc += w2 * ((st[2][c] - sm[2]) * si[2] * gg + bb);
        acc += w3 * ((st[3][c] - sm[3]) * si[3] * gg + bb);
        acc += w4 * ((st[4][c] - sm[4]) * si[4] * gg + bb);
        acc += w5 * ((st[5][c] - sm[5]) * si[5] * gg + bb);
        out[(size_t)b * CC + c] = acc;
    }
}

// ---------------------------------------------------------------------------
extern "C" void kernel_launch(void* const* d_in, const int* in_sizes, int n_in,
                              void* d_out, int out_size, void* d_ws, size_t ws_size,
                              hipStream_t stream)
{
    const float* x      = (const float*)d_in[0];
    const float* pos    = (const float*)d_in[1];
    const float* fc1_w  = (const float*)d_in[2];
    const float* fc2_w  = (const float*)d_in[3];
    const float* ln1_g  = (const float*)d_in[4];
    const float* ln1_b  = (const float*)d_in[5];
    const float* qkv_w  = (const float*)d_in[6];
    const float* qkv_b  = (const float*)d_in[7];
    const float* proj_w = (const float*)d_in[8];
    const float* proj_b = (const float*)d_in[9];
    const float* ln2_g  = (const float*)d_in[10];
    const float* ln2_b  = (const float*)d_in[11];
    const float* mfc1_w = (const float*)d_in[12];
    const float* mfc1_b = (const float*)d_in[13];
    const float* mfc2_w = (const float*)d_in[14];
    const float* mfc2_b = (const float*)d_in[15];
    const float* lnf_g  = (const float*)d_in[16];
    const float* lnf_b  = (const float*)d_in[17];
    const float* wm2_w  = (const float*)d_in[18];
    const float* wm2_b  = (const float*)d_in[19];

    float* ws = (float*)d_ws;
    float* L    = ws;                              // 124416
    float* R    = L + 124416;                      // 124416
    float* pLR  = R + 124416;                      // 486 (+pad)
    float* t    = pLR + 512;                       // 3072*544 f32
    unsigned short* qkvb = (unsigned short*)(t + (size_t)MTOK * CC); // 3072*1632 bf16
    unsigned short* ob  = qkvb + (size_t)MTOK * 3 * CC;              // 3072*544 bf16
    unsigned short* gb  = ob + (size_t)MTOK * CC;                    // 3072*1088 bf16
    unsigned short* wbf = gb + (size_t)MTOK * HID;                   // 4,734,976 bf16

    unsigned short* wqkv = wbf;                         // 2 x (1632*544)
    unsigned short* wprj = wbf + 1775616;               // 2 x (544*544)
    unsigned short* wf1  = wbf + 2367488;               // 2 x (1088*544)
    unsigned short* wf2  = wbf + 3551232;               // 2 x (544*1088)

    // pure-BW pass: x row half-sums || pos row half-sums || weight conversion
    bw_kernel<<<BW_GRID, 256, 0, stream>>>(
        x, pos, qkv_w, proj_w, mfc1_w, mfc2_w, wbf, L, R, pLR);

    // selection + gather (LN now fused into GEMMs)
    select_kernel<<<BB, 128, 0, stream>>>(
        L, R, pLR, fc1_w, fc2_w, x, pos, t);

    for (int i = 0; i < DEPTH; ++i) {
        // qkv: A = LN1(t) fused
        gemm_mfma_kernel<1, 0, 0, 1><<<dim3(13, 24), 256, 0, stream>>>(
            t, wqkv + (size_t)i * 1632 * 544, qkv_b + (size_t)i * 3 * CC,
            nullptr, ln1_g + i * CC, ln1_b + i * CC, qkvb, MTOK, 3 * CC, CC);
        attn_kernel<<<BB, 512, 0, stream>>>(qkvb, (__hip_bfloat16*)ob);
        // proj: A = ob bf16, +res -> t
        gemm_mfma_kernel<0, 0, 1, 0><<<dim3(5, 24), 256, 0, stream>>>(
            ob, wprj + (size_t)i * 544 * 544, proj_b + (size_t)i * CC,
            t, nullptr, nullptr, t, MTOK, CC, CC);
        // mfc1: A = LN2(t) fused, gelu -> gb bf16
        gemm_mfma_kernel<1, 1, 0, 1><<<dim3(9, 24), 256, 0, stream>>>(
            t, wf1 + (size_t)i * HID * 544, mfc1_b + (size_t)i * HID,
            nullptr, ln2_g + i * CC, ln2_b + i * CC, gb, MTOK, HID, CC);
        // mfc2: A = gb bf16, +res -> t
        gemm_mfma_kernel<0, 0, 1, 0><<<dim3(5, 24), 256, 0, stream>>>(
            gb, wf2 + (size_t)i * 544 * HID, mfc2_b + (size_t)i * CC,
            t, nullptr, nullptr, t, MTOK, CC, HID);
    }

    final_kernel<<<BB, 256, 0, stream>>>(t, lnf_g, lnf_b, wm2_w, wm2_b, (float*)d_out);
}